// Round 8
// baseline (2839.850 us; speedup 1.0000x reference)
//
#include <hip/hip_runtime.h>

typedef unsigned short ushort_t;
typedef unsigned int uint_t;

#define SCAN_CHUNK 1024
#define NCH 256          // edge chunks (= pass-A/B grid)
#define BSHIFT 7
#define BNODES 128       // nodes per dst bucket
#define SLICE_SHIFT 13   // 8192 nodes per src slice (1MB bf16 table slice)
#define MAXCELLS 10400   // max (bucket,slice) cells: 800*13 (n<=102400)

__device__ __forceinline__ ushort_t f32_to_bf16(float f) {
    uint_t u = __float_as_uint(f);
    return (ushort_t)((u + 0x7FFF + ((u >> 16) & 1)) >> 16);  // RNE
}
__device__ __forceinline__ float bf16_to_f32(ushort_t h) {
    return __uint_as_float((uint_t)h << 16);
}

// ---------------- pass A: per-chunk (bucket,slice) cell histogram ----------------

__global__ __launch_bounds__(256) void chunk_hist_kernel(const int* __restrict__ src,
                                                         const int* __restrict__ dst,
                                                         int* __restrict__ histG,
                                                         int E, int CELLS, int NSLICE, int chunk) {
    __shared__ int lh[MAXCELLS];
    int c = blockIdx.x;
    for (int i = threadIdx.x; i < CELLS; i += 256) lh[i] = 0;
    __syncthreads();
    int beg = c * chunk, end = min(beg + chunk, E);
    int e = beg + threadIdx.x * 4;
    for (; e + 4 <= end; e += 1024) {
        int4 s4 = *reinterpret_cast<const int4*>(&src[e]);
        int4 d4 = *reinterpret_cast<const int4*>(&dst[e]);
        atomicAdd(&lh[(d4.x >> BSHIFT) * NSLICE + (s4.x >> SLICE_SHIFT)], 1);
        atomicAdd(&lh[(d4.y >> BSHIFT) * NSLICE + (s4.y >> SLICE_SHIFT)], 1);
        atomicAdd(&lh[(d4.z >> BSHIFT) * NSLICE + (s4.z >> SLICE_SHIFT)], 1);
        atomicAdd(&lh[(d4.w >> BSHIFT) * NSLICE + (s4.w >> SLICE_SHIFT)], 1);
    }
    for (; e < end; ++e)
        atomicAdd(&lh[(dst[e] >> BSHIFT) * NSLICE + (src[e] >> SLICE_SHIFT)], 1);
    __syncthreads();
    for (int i = threadIdx.x; i < CELLS; i += 256) histG[(size_t)i * NCH + c] = lh[i];  // cell-major
}

// ---------------- 3-kernel exclusive scan of histG (L entries) ----------------

__global__ void block_sum_kernel(const int* __restrict__ in, int* __restrict__ partials, int L) {
    __shared__ int sdata[256];
    int base = blockIdx.x * SCAN_CHUNK;
    int sum = 0;
    for (int i = threadIdx.x; i < SCAN_CHUNK; i += 256) {
        int idx = base + i;
        sum += (idx < L) ? in[idx] : 0;
    }
    sdata[threadIdx.x] = sum;
    __syncthreads();
    for (int s = 128; s > 0; s >>= 1) {
        if (threadIdx.x < s) sdata[threadIdx.x] += sdata[threadIdx.x + s];
        __syncthreads();
    }
    if (threadIdx.x == 0) partials[blockIdx.x] = sdata[0];
}

// parallel in-place exclusive scan of partials (nb <= 256*PER), writes total to out[L]
__global__ __launch_bounds__(256) void scan_partials_kernel(int* __restrict__ partials, int nb,
                                                            int* __restrict__ out, int L) {
    __shared__ int sdata[256];
    int per = (nb + 255) / 256;
    int base = threadIdx.x * per;
    int tsum = 0;
    for (int j = 0; j < per; j++) { int i = base + j; tsum += (i < nb) ? partials[i] : 0; }
    sdata[threadIdx.x] = tsum;
    __syncthreads();
    for (int s = 1; s < 256; s <<= 1) {
        int v = (threadIdx.x >= s) ? sdata[threadIdx.x - s] : 0;
        __syncthreads();
        sdata[threadIdx.x] += v;
        __syncthreads();
    }
    int off = (threadIdx.x == 0) ? 0 : sdata[threadIdx.x - 1];
    for (int j = 0; j < per; j++) {
        int i = base + j;
        if (i < nb) { int v = partials[i]; partials[i] = off; off += v; }
    }
    if (threadIdx.x == 255) out[L] = sdata[255];  // total = E
}

__global__ void scan_write_kernel(const int* __restrict__ in, const int* __restrict__ partials,
                                  int* __restrict__ out, int L) {
    __shared__ int sdata[256];
    int base = blockIdx.x * SCAN_CHUNK;
    int tbase = base + threadIdx.x * 4;
    int vals[4];
    int tsum = 0;
    #pragma unroll
    for (int j = 0; j < 4; j++) {
        int idx = tbase + j;
        vals[j] = (idx < L) ? in[idx] : 0;
        tsum += vals[j];
    }
    sdata[threadIdx.x] = tsum;
    __syncthreads();
    for (int s = 1; s < 256; s <<= 1) {
        int v = (threadIdx.x >= s) ? sdata[threadIdx.x - s] : 0;
        __syncthreads();
        sdata[threadIdx.x] += v;
        __syncthreads();
    }
    int excl = (threadIdx.x == 0) ? 0 : sdata[threadIdx.x - 1];
    int offset = partials[blockIdx.x] + excl;
    #pragma unroll
    for (int j = 0; j < 4; j++) {
        int idx = tbase + j;
        if (idx < L) out[idx] = offset;
        offset += vals[j];
    }
}

// ---------------- pass B: scatter packed (src|ldst<<24) into (cell,chunk) windows ----------------

__global__ __launch_bounds__(256) void chunk_scatter_kernel(const int* __restrict__ src,
                                                            const int* __restrict__ dst,
                                                            const int* __restrict__ histBase,
                                                            int* __restrict__ binned,
                                                            int E, int CELLS, int NSLICE, int chunk) {
    __shared__ int cur[MAXCELLS];
    int c = blockIdx.x;
    for (int i = threadIdx.x; i < CELLS; i += 256) cur[i] = histBase[(size_t)i * NCH + c];
    __syncthreads();
    int beg = c * chunk, end = min(beg + chunk, E);
    int e = beg + threadIdx.x * 4;
    for (; e + 4 <= end; e += 1024) {
        int4 s4 = *reinterpret_cast<const int4*>(&src[e]);
        int4 d4 = *reinterpret_cast<const int4*>(&dst[e]);
        int p0 = atomicAdd(&cur[(d4.x >> BSHIFT) * NSLICE + (s4.x >> SLICE_SHIFT)], 1);
        binned[p0] = s4.x | ((d4.x & (BNODES - 1)) << 24);
        int p1 = atomicAdd(&cur[(d4.y >> BSHIFT) * NSLICE + (s4.y >> SLICE_SHIFT)], 1);
        binned[p1] = s4.y | ((d4.y & (BNODES - 1)) << 24);
        int p2 = atomicAdd(&cur[(d4.z >> BSHIFT) * NSLICE + (s4.z >> SLICE_SHIFT)], 1);
        binned[p2] = s4.z | ((d4.z & (BNODES - 1)) << 24);
        int p3 = atomicAdd(&cur[(d4.w >> BSHIFT) * NSLICE + (s4.w >> SLICE_SHIFT)], 1);
        binned[p3] = s4.w | ((d4.w & (BNODES - 1)) << 24);
    }
    for (; e < end; ++e) {
        int s = src[e], d = dst[e];
        int pos = atomicAdd(&cur[(d >> BSHIFT) * NSLICE + (s >> SLICE_SHIFT)], 1);
        binned[pos] = s | ((d & (BNODES - 1)) << 24);
    }
}

// ---------------- per-bucket degree -> dinv ----------------

__global__ __launch_bounds__(256) void bucket_degree_kernel(const int* __restrict__ binned,
                                                            const int* __restrict__ histBase,
                                                            float* __restrict__ dinv,
                                                            int n, int NSLICE) {
    __shared__ int cnt[BNODES];
    int b = blockIdx.x;
    int tid = threadIdx.x;
    if (tid < BNODES) cnt[tid] = 0;
    __syncthreads();
    int beg = histBase[(size_t)b * NSLICE * NCH];
    int end = histBase[(size_t)(b + 1) * NSLICE * NCH];
    for (int e = beg + tid; e < end; e += 256)
        atomicAdd(&cnt[(uint_t)binned[e] >> 24], 1);
    __syncthreads();
    int node = (b << BSHIFT) + tid;
    if (tid < BNODES && node < n) dinv[node] = rsqrtf((float)(cnt[tid] + 1));  // +1 self-loop
}

// ---------------- dense transform: g[r][c] = bf16(dinv[r] * sum_k in[r][k]*W[k][c]) ----------------

__global__ __launch_bounds__(256) void transform_kernel(const float* __restrict__ in,
                                                        const float* __restrict__ W,
                                                        const float* __restrict__ dinv,
                                                        ushort_t* __restrict__ g, int n) {
    __shared__ float xs[4 * 256];                 // 4 waves/block x (4 rows x 64 floats)
    int lane = threadIdx.x & 63;
    int wslot = threadIdx.x >> 6;
    float* myxs = &xs[wslot * 256];

    float wreg[64];                               // W[k][lane] in VGPRs
    #pragma unroll
    for (int k = 0; k < 64; k++) wreg[k] = W[k * 64 + lane];

    int wave = (blockIdx.x * 256 + threadIdx.x) >> 6;
    int nwaves = gridDim.x * 4;
    int ngroups = (n + 3) >> 2;
    for (int grp = wave; grp < ngroups; grp += nwaves) {
        int r0 = grp * 4;
        if (r0 + 4 <= n) {
            float4 xv = *reinterpret_cast<const float4*>(&in[(size_t)r0 * 64 + lane * 4]);
            *reinterpret_cast<float4*>(&myxs[lane * 4]) = xv;
            float acc0 = 0.f, acc1 = 0.f, acc2 = 0.f, acc3 = 0.f;
            #pragma unroll
            for (int k4 = 0; k4 < 16; k4++) {
                float4 a = *reinterpret_cast<const float4*>(&myxs[0 * 64 + k4 * 4]);
                float4 b = *reinterpret_cast<const float4*>(&myxs[1 * 64 + k4 * 4]);
                float4 c = *reinterpret_cast<const float4*>(&myxs[2 * 64 + k4 * 4]);
                float4 d = *reinterpret_cast<const float4*>(&myxs[3 * 64 + k4 * 4]);
                float w0 = wreg[k4 * 4 + 0], w1 = wreg[k4 * 4 + 1];
                float w2 = wreg[k4 * 4 + 2], w3 = wreg[k4 * 4 + 3];
                acc0 = fmaf(a.x, w0, acc0); acc0 = fmaf(a.y, w1, acc0);
                acc0 = fmaf(a.z, w2, acc0); acc0 = fmaf(a.w, w3, acc0);
                acc1 = fmaf(b.x, w0, acc1); acc1 = fmaf(b.y, w1, acc1);
                acc1 = fmaf(b.z, w2, acc1); acc1 = fmaf(b.w, w3, acc1);
                acc2 = fmaf(c.x, w0, acc2); acc2 = fmaf(c.y, w1, acc2);
                acc2 = fmaf(c.z, w2, acc2); acc2 = fmaf(c.w, w3, acc2);
                acc3 = fmaf(d.x, w0, acc3); acc3 = fmaf(d.y, w1, acc3);
                acc3 = fmaf(d.z, w2, acc3); acc3 = fmaf(d.w, w3, acc3);
            }
            g[(size_t)(r0 + 0) * 64 + lane] = f32_to_bf16(acc0 * dinv[r0 + 0]);
            g[(size_t)(r0 + 1) * 64 + lane] = f32_to_bf16(acc1 * dinv[r0 + 1]);
            g[(size_t)(r0 + 2) * 64 + lane] = f32_to_bf16(acc2 * dinv[r0 + 2]);
            g[(size_t)(r0 + 3) * 64 + lane] = f32_to_bf16(acc3 * dinv[r0 + 3]);
        } else {
            for (int r = r0; r < n; r++) {
                float acc = 0.f;
                #pragma unroll
                for (int k = 0; k < 64; k++) acc = fmaf(in[(size_t)r * 64 + k], wreg[k], acc);
                g[(size_t)r * 64 + lane] = f32_to_bf16(acc * dinv[r]);
            }
        }
    }
}

// ---------------- fused aggregate: per-bucket LDS accumulators, src-slice-ordered edges ----------------
// Block b owns 128 dst nodes (32KB f32 acc, 4 blocks/CU). Edges of the bucket are pre-sorted
// by src slice (8192 nodes = 1MB of g), so all blocks sweep the table slice-by-slice in rough
// lockstep -> gathers hit XCD L2. Stride-4 edge loop keeps the block's 4 waves in the same
// slice window; unroll-8 gives 8 gathers in flight per wave. Full 128B rows (R7 lesson).

__global__ __launch_bounds__(256) void fused_agg_kernel(const ushort_t* __restrict__ g,
                                                        const int* __restrict__ histBase,
                                                        const int* __restrict__ binned,
                                                        const float* __restrict__ dinv,
                                                        const float* __restrict__ bias,
                                                        float* __restrict__ out,
                                                        int n, int NSLICE, int relu) {
    __shared__ float accS[BNODES * 64];           // 32KB
    int b = blockIdx.x;
    int tid = threadIdx.x;
    int lane = tid & 63;
    int w = tid >> 6;
    for (int i = tid; i < BNODES * 16; i += 256)
        *reinterpret_cast<float4*>(&accS[i * 4]) = make_float4(0.f, 0.f, 0.f, 0.f);
    __syncthreads();
    int beg = histBase[(size_t)b * NSLICE * NCH];
    int end = histBase[(size_t)(b + 1) * NSLICE * NCH];
    int e = beg + w;
    for (; e + 28 < end; e += 32) {               // 8 edges per wave per iter, waves interleaved
        int v0 = binned[e +  0], v1 = binned[e +  4], v2 = binned[e +  8], v3 = binned[e + 12];
        int v4 = binned[e + 16], v5 = binned[e + 20], v6 = binned[e + 24], v7 = binned[e + 28];
        float f0 = bf16_to_f32(g[(size_t)(v0 & 0xFFFFFF) * 64 + lane]);
        float f1 = bf16_to_f32(g[(size_t)(v1 & 0xFFFFFF) * 64 + lane]);
        float f2 = bf16_to_f32(g[(size_t)(v2 & 0xFFFFFF) * 64 + lane]);
        float f3 = bf16_to_f32(g[(size_t)(v3 & 0xFFFFFF) * 64 + lane]);
        float f4 = bf16_to_f32(g[(size_t)(v4 & 0xFFFFFF) * 64 + lane]);
        float f5 = bf16_to_f32(g[(size_t)(v5 & 0xFFFFFF) * 64 + lane]);
        float f6 = bf16_to_f32(g[(size_t)(v6 & 0xFFFFFF) * 64 + lane]);
        float f7 = bf16_to_f32(g[(size_t)(v7 & 0xFFFFFF) * 64 + lane]);
        atomicAdd(&accS[((uint_t)v0 >> 24) * 64 + lane], f0);
        atomicAdd(&accS[((uint_t)v1 >> 24) * 64 + lane], f1);
        atomicAdd(&accS[((uint_t)v2 >> 24) * 64 + lane], f2);
        atomicAdd(&accS[((uint_t)v3 >> 24) * 64 + lane], f3);
        atomicAdd(&accS[((uint_t)v4 >> 24) * 64 + lane], f4);
        atomicAdd(&accS[((uint_t)v5 >> 24) * 64 + lane], f5);
        atomicAdd(&accS[((uint_t)v6 >> 24) * 64 + lane], f6);
        atomicAdd(&accS[((uint_t)v7 >> 24) * 64 + lane], f7);
    }
    for (; e < end; e += 4) {
        int v = binned[e];
        float f = bf16_to_f32(g[(size_t)(v & 0xFFFFFF) * 64 + lane]);
        atomicAdd(&accS[((uint_t)v >> 24) * 64 + lane], f);
    }
    __syncthreads();
    float bl = bias[lane];
    for (int l = w; l < BNODES; l += 4) {
        int node = (b << BSHIFT) + l;
        if (node >= n) break;
        float a = accS[l * 64 + lane] + bf16_to_f32(g[(size_t)node * 64 + lane]);  // + self
        float o = fmaf(dinv[node], a, bl);
        out[(size_t)node * 64 + lane] = relu ? fmaxf(o, 0.f) : o;
    }
}

extern "C" void kernel_launch(void* const* d_in, const int* in_sizes, int n_in,
                              void* d_out, int out_size, void* d_ws, size_t ws_size,
                              hipStream_t stream) {
    const float* x  = (const float*)d_in[0];
    const int*   ei = (const int*)d_in[1];
    const float* W1 = (const float*)d_in[2];
    const float* b1 = (const float*)d_in[3];
    const float* W2 = (const float*)d_in[4];
    const float* b2 = (const float*)d_in[5];
    float* out = (float*)d_out;

    const int n = in_sizes[0] / 64;      // 100000
    const int E = in_sizes[1] / 2;       // 3200000
    const int* src = ei;
    const int* dst = ei + E;
    const int NB = (n + BNODES - 1) >> BSHIFT;                  // 782 buckets
    const int NSLICE = (n + (1 << SLICE_SHIFT) - 1) >> SLICE_SHIFT;  // 13 slices
    const int CELLS = NB * NSLICE;                              // 10166
    const int chunk = (E + NCH - 1) / NCH;                      // 12500 edges/chunk
    const int L = CELLS * NCH;                                  // 2.6M

    // workspace carve-up (256B aligned)
    char* ws = (char*)d_ws;
    size_t off = 0;
    auto carve = [&](size_t bytes) { char* p = ws + off; off = (off + bytes + 255) & ~(size_t)255; return p; };
    int*      partials = (int*)     carve(16384);
    float*    dinv     = (float*)   carve((size_t)n * 4);
    int*      histG    = (int*)     carve((size_t)L * 4);        // 10.4MB
    int*      histBase = (int*)     carve((size_t)(L + 1) * 4);  // 10.4MB
    int*      binned   = (int*)     carve((size_t)E * 4);        // packed src|ldst<<24
    ushort_t* g        = (ushort_t*)carve((size_t)n * 64 * 2);   // bf16 scaled features

    const int nbs = (L + SCAN_CHUNK - 1) / SCAN_CHUNK;           // ~2542

    // ---- (bucket,slice) radix partition (shared by both layers) ----
    chunk_hist_kernel<<<NCH, 256, 0, stream>>>(src, dst, histG, E, CELLS, NSLICE, chunk);
    block_sum_kernel<<<nbs, 256, 0, stream>>>(histG, partials, L);
    scan_partials_kernel<<<1, 256, 0, stream>>>(partials, nbs, histBase, L);
    scan_write_kernel<<<nbs, 256, 0, stream>>>(histG, partials, histBase, L);
    chunk_scatter_kernel<<<NCH, 256, 0, stream>>>(src, dst, histBase, binned, E, CELLS, NSLICE, chunk);
    bucket_degree_kernel<<<NB, 256, 0, stream>>>(binned, histBase, dinv, n, NSLICE);

    // ---- layer 1: g = bf16((x@W1)*dinv) ; h1 = relu(dinv*(agg(g)+g)+b1) -> d_out (f32) ----
    transform_kernel<<<2048, 256, 0, stream>>>(x, W1, dinv, g, n);
    fused_agg_kernel<<<NB, 256, 0, stream>>>(g, histBase, binned, dinv, b1, out, n, NSLICE, 1);

    // ---- layer 2: g = bf16((h1@W2)*dinv) ; out = dinv*(agg(g)+g)+b2 ----
    transform_kernel<<<2048, 256, 0, stream>>>(out, W2, dinv, g, n);
    fused_agg_kernel<<<NB, 256, 0, stream>>>(g, histBase, binned, dinv, b2, out, n, NSLICE, 0);
}

// Round 9
// 239.430 us; speedup vs baseline: 11.8609x; 11.8609x over previous
//
#include <hip/hip_runtime.h>

typedef unsigned short ushort_t;
typedef unsigned int uint_t;

#define SCAN_CHUNK 1024
#define NCH 256          // edge chunks (= pass-A/B grid)
#define BSHIFT 8
#define BNODES 256       // nodes per bucket
#define MAXNB 512        // max buckets (n <= 131072)

__device__ __forceinline__ ushort_t f32_to_bf16(float f) {
    uint_t u = __float_as_uint(f);
    return (ushort_t)((u + 0x7FFF + ((u >> 16) & 1)) >> 16);  // RNE
}
__device__ __forceinline__ float bf16_to_f32(ushort_t h) {
    return __uint_as_float((uint_t)h << 16);
}

// ---------------- pass A: per-chunk bucket histogram ----------------

__global__ __launch_bounds__(256) void chunk_hist_kernel(const int* __restrict__ dst,
                                                         int* __restrict__ histG,
                                                         int E, int NB, int chunk) {
    __shared__ int lh[MAXNB];
    int c = blockIdx.x;
    for (int i = threadIdx.x; i < NB; i += 256) lh[i] = 0;
    __syncthreads();
    int beg = c * chunk, end = min(beg + chunk, E);
    int e = beg + threadIdx.x * 4;
    for (; e + 4 <= end; e += 1024) {
        int4 d4 = *reinterpret_cast<const int4*>(&dst[e]);
        atomicAdd(&lh[d4.x >> BSHIFT], 1);
        atomicAdd(&lh[d4.y >> BSHIFT], 1);
        atomicAdd(&lh[d4.z >> BSHIFT], 1);
        atomicAdd(&lh[d4.w >> BSHIFT], 1);
    }
    for (; e < end; ++e) atomicAdd(&lh[dst[e] >> BSHIFT], 1);
    __syncthreads();
    for (int i = threadIdx.x; i < NB; i += 256) histG[i * NCH + c] = lh[i];  // bucket-major
}

// ---------------- 3-kernel exclusive scan of histG (L entries) ----------------

__global__ void block_sum_kernel(const int* __restrict__ in, int* __restrict__ partials, int L) {
    __shared__ int sdata[256];
    int base = blockIdx.x * SCAN_CHUNK;
    int sum = 0;
    for (int i = threadIdx.x; i < SCAN_CHUNK; i += 256) {
        int idx = base + i;
        sum += (idx < L) ? in[idx] : 0;
    }
    sdata[threadIdx.x] = sum;
    __syncthreads();
    for (int s = 128; s > 0; s >>= 1) {
        if (threadIdx.x < s) sdata[threadIdx.x] += sdata[threadIdx.x + s];
        __syncthreads();
    }
    if (threadIdx.x == 0) partials[blockIdx.x] = sdata[0];
}

__global__ void scan_partials_kernel(int* __restrict__ partials, int nb,
                                     int* __restrict__ out, int L) {
    if (threadIdx.x == 0 && blockIdx.x == 0) {
        int acc = 0;
        for (int i = 0; i < nb; i++) { int v = partials[i]; partials[i] = acc; acc += v; }
        out[L] = acc;  // total = E
    }
}

__global__ void scan_write_kernel(const int* __restrict__ in, const int* __restrict__ partials,
                                  int* __restrict__ out, int L) {
    __shared__ int sdata[256];
    int base = blockIdx.x * SCAN_CHUNK;
    int tbase = base + threadIdx.x * 4;
    int vals[4];
    int tsum = 0;
    #pragma unroll
    for (int j = 0; j < 4; j++) {
        int idx = tbase + j;
        vals[j] = (idx < L) ? in[idx] : 0;
        tsum += vals[j];
    }
    sdata[threadIdx.x] = tsum;
    __syncthreads();
    for (int s = 1; s < 256; s <<= 1) {
        int v = (threadIdx.x >= s) ? sdata[threadIdx.x - s] : 0;
        __syncthreads();
        sdata[threadIdx.x] += v;
        __syncthreads();
    }
    int excl = (threadIdx.x == 0) ? 0 : sdata[threadIdx.x - 1];
    int offset = partials[blockIdx.x] + excl;
    #pragma unroll
    for (int j = 0; j < 4; j++) {
        int idx = tbase + j;
        if (idx < L) out[idx] = offset;
        offset += vals[j];
    }
}

// ---------------- pass B: scatter packed (src|ldst<<24) into (bucket,chunk) windows ----------------

__global__ __launch_bounds__(256) void chunk_scatter_kernel(const int* __restrict__ src,
                                                            const int* __restrict__ dst,
                                                            const int* __restrict__ histBase,
                                                            int* __restrict__ binned,
                                                            int E, int NB, int chunk) {
    __shared__ int cur[MAXNB];
    int c = blockIdx.x;
    for (int i = threadIdx.x; i < NB; i += 256) cur[i] = histBase[i * NCH + c];
    __syncthreads();
    int beg = c * chunk, end = min(beg + chunk, E);
    int e = beg + threadIdx.x * 4;
    for (; e + 4 <= end; e += 1024) {
        int4 s4 = *reinterpret_cast<const int4*>(&src[e]);
        int4 d4 = *reinterpret_cast<const int4*>(&dst[e]);
        int p0 = atomicAdd(&cur[d4.x >> BSHIFT], 1);
        binned[p0] = s4.x | ((d4.x & (BNODES - 1)) << 24);
        int p1 = atomicAdd(&cur[d4.y >> BSHIFT], 1);
        binned[p1] = s4.y | ((d4.y & (BNODES - 1)) << 24);
        int p2 = atomicAdd(&cur[d4.z >> BSHIFT], 1);
        binned[p2] = s4.z | ((d4.z & (BNODES - 1)) << 24);
        int p3 = atomicAdd(&cur[d4.w >> BSHIFT], 1);
        binned[p3] = s4.w | ((d4.w & (BNODES - 1)) << 24);
    }
    for (; e < end; ++e) {
        int s = src[e], d = dst[e];
        int pos = atomicAdd(&cur[d >> BSHIFT], 1);
        binned[pos] = s | ((d & (BNODES - 1)) << 24);
    }
}

// ---------------- fused per-bucket: node hist + local scan -> row_ptr/dinv + CSR scatter ----------------

__global__ __launch_bounds__(256) void bucket_finalize_kernel(const int* __restrict__ binned,
                                                              const int* __restrict__ histBase,
                                                              int* __restrict__ row_ptr,
                                                              float* __restrict__ dinv,
                                                              int* __restrict__ srcidx, int n) {
    __shared__ int cl[BNODES];   // counts, then cursors
    __shared__ int sl[BNODES];   // scan workspace
    int b = blockIdx.x;
    int tid = threadIdx.x;
    cl[tid] = 0;
    __syncthreads();
    int beg = histBase[b * NCH], end = histBase[(b + 1) * NCH];
    for (int e = beg + tid; e < end; e += 256)
        atomicAdd(&cl[(uint_t)binned[e] >> 24], 1);
    __syncthreads();
    int mycnt = cl[tid];
    sl[tid] = mycnt;
    __syncthreads();
    for (int s = 1; s < 256; s <<= 1) {           // Hillis-Steele inclusive
        int v = (tid >= s) ? sl[tid - s] : 0;
        __syncthreads();
        sl[tid] += v;
        __syncthreads();
    }
    int excl = tid ? sl[tid - 1] : 0;
    int myrp = beg + excl;
    cl[tid] = myrp;                               // becomes fill cursor
    int node = (b << BSHIFT) + tid;
    if (node < n) {
        row_ptr[node] = myrp;
        dinv[node] = rsqrtf((float)(mycnt + 1));  // +1 self-loop
        if (node == n - 1) row_ptr[n] = myrp + mycnt;
    }
    __syncthreads();
    for (int e = beg + tid; e < end; e += 256) {  // binned slice is L2-hot from pass 1
        int v = binned[e];
        int pos = atomicAdd(&cl[(uint_t)v >> 24], 1);
        srcidx[pos] = v & 0xFFFFFF;
    }
}

// ---------------- dense transform: g[r][c] = bf16(dinv[r] * sum_k in[r][k]*W[k][c]) ----------------

__global__ __launch_bounds__(256) void transform_kernel(const float* __restrict__ in,
                                                        const float* __restrict__ W,
                                                        const float* __restrict__ dinv,
                                                        ushort_t* __restrict__ g, int n) {
    __shared__ float xs[4 * 256];                 // 4 waves/block x (4 rows x 64 floats)
    int lane = threadIdx.x & 63;
    int wslot = threadIdx.x >> 6;
    float* myxs = &xs[wslot * 256];

    float wreg[64];                               // W[k][lane] in VGPRs
    #pragma unroll
    for (int k = 0; k < 64; k++) wreg[k] = W[k * 64 + lane];

    int wave = (blockIdx.x * 256 + threadIdx.x) >> 6;
    int nwaves = gridDim.x * 4;
    int ngroups = (n + 3) >> 2;
    for (int grp = wave; grp < ngroups; grp += nwaves) {
        int r0 = grp * 4;
        if (r0 + 4 <= n) {
            float4 xv = *reinterpret_cast<const float4*>(&in[(size_t)r0 * 64 + lane * 4]);
            *reinterpret_cast<float4*>(&myxs[lane * 4]) = xv;
            float acc0 = 0.f, acc1 = 0.f, acc2 = 0.f, acc3 = 0.f;
            #pragma unroll
            for (int k4 = 0; k4 < 16; k4++) {
                float4 a = *reinterpret_cast<const float4*>(&myxs[0 * 64 + k4 * 4]);
                float4 b = *reinterpret_cast<const float4*>(&myxs[1 * 64 + k4 * 4]);
                float4 c = *reinterpret_cast<const float4*>(&myxs[2 * 64 + k4 * 4]);
                float4 d = *reinterpret_cast<const float4*>(&myxs[3 * 64 + k4 * 4]);
                float w0 = wreg[k4 * 4 + 0], w1 = wreg[k4 * 4 + 1];
                float w2 = wreg[k4 * 4 + 2], w3 = wreg[k4 * 4 + 3];
                acc0 = fmaf(a.x, w0, acc0); acc0 = fmaf(a.y, w1, acc0);
                acc0 = fmaf(a.z, w2, acc0); acc0 = fmaf(a.w, w3, acc0);
                acc1 = fmaf(b.x, w0, acc1); acc1 = fmaf(b.y, w1, acc1);
                acc1 = fmaf(b.z, w2, acc1); acc1 = fmaf(b.w, w3, acc1);
                acc2 = fmaf(c.x, w0, acc2); acc2 = fmaf(c.y, w1, acc2);
                acc2 = fmaf(c.z, w2, acc2); acc2 = fmaf(c.w, w3, acc2);
                acc3 = fmaf(d.x, w0, acc3); acc3 = fmaf(d.y, w1, acc3);
                acc3 = fmaf(d.z, w2, acc3); acc3 = fmaf(d.w, w3, acc3);
            }
            g[(size_t)(r0 + 0) * 64 + lane] = f32_to_bf16(acc0 * dinv[r0 + 0]);
            g[(size_t)(r0 + 1) * 64 + lane] = f32_to_bf16(acc1 * dinv[r0 + 1]);
            g[(size_t)(r0 + 2) * 64 + lane] = f32_to_bf16(acc2 * dinv[r0 + 2]);
            g[(size_t)(r0 + 3) * 64 + lane] = f32_to_bf16(acc3 * dinv[r0 + 3]);
        } else {
            for (int r = r0; r < n; r++) {
                float acc = 0.f;
                #pragma unroll
                for (int k = 0; k < 64; k++) acc = fmaf(in[(size_t)r * 64 + k], wreg[k], acc);
                g[(size_t)r * 64 + lane] = f32_to_bf16(acc * dinv[r]);
            }
        }
    }
}

// ---------------- aggregate: one wave per node, 16 gathers in flight (two sum trees) ----------------

__global__ __launch_bounds__(256) void aggregate_kernel(const ushort_t* __restrict__ g,
                                                        const int* __restrict__ row_ptr,
                                                        const int* __restrict__ srcidx,
                                                        const float* __restrict__ dinv,
                                                        const float* __restrict__ b,
                                                        float* __restrict__ out, int n, int relu) {
    int lane = threadIdx.x & 63;
    int node = (blockIdx.x * 256 + threadIdx.x) >> 6;
    if (node >= n) return;
    node = __builtin_amdgcn_readfirstlane(node);
    int beg = row_ptr[node];
    int end = row_ptr[node + 1];
    const ushort_t* gl = g + lane;
    float acc = bf16_to_f32(gl[(size_t)node * 64]);  // self-loop (g has dinv folded)
    int e = beg;
    for (; e + 16 <= end; e += 16) {
        int s0 = srcidx[e + 0],  s1 = srcidx[e + 1],  s2 = srcidx[e + 2],  s3 = srcidx[e + 3];
        int s4 = srcidx[e + 4],  s5 = srcidx[e + 5],  s6 = srcidx[e + 6],  s7 = srcidx[e + 7];
        int s8 = srcidx[e + 8],  s9 = srcidx[e + 9],  sa = srcidx[e + 10], sb = srcidx[e + 11];
        int sc = srcidx[e + 12], sd = srcidx[e + 13], se = srcidx[e + 14], sf = srcidx[e + 15];
        float v0 = bf16_to_f32(gl[(size_t)s0 * 64]);
        float v1 = bf16_to_f32(gl[(size_t)s1 * 64]);
        float v2 = bf16_to_f32(gl[(size_t)s2 * 64]);
        float v3 = bf16_to_f32(gl[(size_t)s3 * 64]);
        float v4 = bf16_to_f32(gl[(size_t)s4 * 64]);
        float v5 = bf16_to_f32(gl[(size_t)s5 * 64]);
        float v6 = bf16_to_f32(gl[(size_t)s6 * 64]);
        float v7 = bf16_to_f32(gl[(size_t)s7 * 64]);
        float v8 = bf16_to_f32(gl[(size_t)s8 * 64]);
        float v9 = bf16_to_f32(gl[(size_t)s9 * 64]);
        float va = bf16_to_f32(gl[(size_t)sa * 64]);
        float vb = bf16_to_f32(gl[(size_t)sb * 64]);
        float vc = bf16_to_f32(gl[(size_t)sc * 64]);
        float vd = bf16_to_f32(gl[(size_t)sd * 64]);
        float ve = bf16_to_f32(gl[(size_t)se * 64]);
        float vf = bf16_to_f32(gl[(size_t)sf * 64]);
        float t0 = ((v0 + v1) + (v2 + v3)) + ((v4 + v5) + (v6 + v7));
        float t1 = ((v8 + v9) + (va + vb)) + ((vc + vd) + (ve + vf));
        acc += t0 + t1;
    }
    for (; e + 4 <= end; e += 4) {
        int s0 = srcidx[e + 0], s1 = srcidx[e + 1], s2 = srcidx[e + 2], s3 = srcidx[e + 3];
        float v0 = bf16_to_f32(gl[(size_t)s0 * 64]);
        float v1 = bf16_to_f32(gl[(size_t)s1 * 64]);
        float v2 = bf16_to_f32(gl[(size_t)s2 * 64]);
        float v3 = bf16_to_f32(gl[(size_t)s3 * 64]);
        acc += (v0 + v1) + (v2 + v3);
    }
    for (; e < end; ++e) acc += bf16_to_f32(gl[(size_t)srcidx[e] * 64]);
    float o = fmaf(dinv[node], acc, b[lane]);
    out[(size_t)node * 64 + lane] = relu ? fmaxf(o, 0.f) : o;
}

extern "C" void kernel_launch(void* const* d_in, const int* in_sizes, int n_in,
                              void* d_out, int out_size, void* d_ws, size_t ws_size,
                              hipStream_t stream) {
    const float* x  = (const float*)d_in[0];
    const int*   ei = (const int*)d_in[1];
    const float* W1 = (const float*)d_in[2];
    const float* b1 = (const float*)d_in[3];
    const float* W2 = (const float*)d_in[4];
    const float* b2 = (const float*)d_in[5];
    float* out = (float*)d_out;

    const int n = in_sizes[0] / 64;      // 100000
    const int E = in_sizes[1] / 2;       // 3200000
    const int* src = ei;
    const int* dst = ei + E;
    const int NB = (n + BNODES - 1) >> BSHIFT;         // 391 buckets
    const int chunk = (E + NCH - 1) / NCH;             // 12500 edges/chunk
    const int L = NB * NCH;                            // histogram length

    // workspace carve-up (256B aligned)
    char* ws = (char*)d_ws;
    size_t off = 0;
    auto carve = [&](size_t bytes) { char* p = ws + off; off = (off + bytes + 255) & ~(size_t)255; return p; };
    int*      row_ptr  = (int*)     carve((size_t)(n + 1) * 4);
    int*      partials = (int*)     carve(4096);
    float*    dinv     = (float*)   carve((size_t)n * 4);
    int*      histG    = (int*)     carve((size_t)L * 4);
    int*      histBase = (int*)     carve((size_t)(L + 1) * 4);
    int*      srcidx   = (int*)     carve((size_t)E * 4);
    int*      binned   = (int*)     carve((size_t)E * 4);        // packed src|ldst<<24
    ushort_t* g        = (ushort_t*)carve((size_t)n * 64 * 2);   // bf16 scaled features

    const int nbs_hist = (L + SCAN_CHUNK - 1) / SCAN_CHUNK;

    // ---- CSR build via chunked two-pass radix partition (shared by both layers) ----
    chunk_hist_kernel<<<NCH, 256, 0, stream>>>(dst, histG, E, NB, chunk);
    block_sum_kernel<<<nbs_hist, 256, 0, stream>>>(histG, partials, L);
    scan_partials_kernel<<<1, 64, 0, stream>>>(partials, nbs_hist, histBase, L);
    scan_write_kernel<<<nbs_hist, 256, 0, stream>>>(histG, partials, histBase, L);
    chunk_scatter_kernel<<<NCH, 256, 0, stream>>>(src, dst, histBase, binned, E, NB, chunk);
    bucket_finalize_kernel<<<NB, 256, 0, stream>>>(binned, histBase, row_ptr, dinv, srcidx, n);

    const int agg_grid = (n * 64 + 255) / 256;   // one wave per node

    // ---- layer 1: g = bf16((x@W1)*dinv) ; h1 = relu(dinv*(agg(g)+g)+b1) -> d_out (f32) ----
    transform_kernel<<<2048, 256, 0, stream>>>(x, W1, dinv, g, n);
    aggregate_kernel<<<agg_grid, 256, 0, stream>>>(g, row_ptr, srcidx, dinv, b1, out, n, 1);

    // ---- layer 2: g = bf16((h1@W2)*dinv) ; out = dinv*(agg(g)+g)+b2 ----
    transform_kernel<<<2048, 256, 0, stream>>>(out, W2, dinv, g, n);
    aggregate_kernel<<<agg_grid, 256, 0, stream>>>(g, row_ptr, srcidx, dinv, b2, out, n, 0);
}

// Round 10
// 232.981 us; speedup vs baseline: 12.1892x; 1.0277x over previous
//
#include <hip/hip_runtime.h>

typedef unsigned short ushort_t;
typedef unsigned int uint_t;

#define SCAN_CHUNK 1024
#define NCH 256          // edge chunks (= pass-A/B grid)
#define HTHREADS 1024    // threads for chunk hist/scatter (16 waves/CU)
#define BSHIFT 8
#define BNODES 256       // nodes per bucket
#define MAXNB 512        // max buckets (n <= 131072)

__device__ __forceinline__ ushort_t f32_to_bf16(float f) {
    uint_t u = __float_as_uint(f);
    return (ushort_t)((u + 0x7FFF + ((u >> 16) & 1)) >> 16);  // RNE
}
__device__ __forceinline__ float bf16_to_f32(ushort_t h) {
    return __uint_as_float((uint_t)h << 16);
}

// ---------------- pass A: per-chunk bucket histogram ----------------

__global__ __launch_bounds__(HTHREADS) void chunk_hist_kernel(const int* __restrict__ dst,
                                                              int* __restrict__ histG,
                                                              int E, int NB, int chunk) {
    __shared__ int lh[MAXNB];
    int c = blockIdx.x;
    for (int i = threadIdx.x; i < NB; i += HTHREADS) lh[i] = 0;
    __syncthreads();
    int beg = c * chunk, end = min(beg + chunk, E);
    int e = beg + threadIdx.x * 4;
    for (; e + 4 <= end; e += HTHREADS * 4) {
        int4 d4 = *reinterpret_cast<const int4*>(&dst[e]);
        atomicAdd(&lh[d4.x >> BSHIFT], 1);
        atomicAdd(&lh[d4.y >> BSHIFT], 1);
        atomicAdd(&lh[d4.z >> BSHIFT], 1);
        atomicAdd(&lh[d4.w >> BSHIFT], 1);
    }
    for (; e < end; ++e) atomicAdd(&lh[dst[e] >> BSHIFT], 1);
    __syncthreads();
    for (int i = threadIdx.x; i < NB; i += HTHREADS) histG[i * NCH + c] = lh[i];  // bucket-major
}

// ---------------- 3-kernel exclusive scan of histG (L entries) ----------------

__global__ void block_sum_kernel(const int* __restrict__ in, int* __restrict__ partials, int L) {
    __shared__ int sdata[256];
    int base = blockIdx.x * SCAN_CHUNK;
    int sum = 0;
    for (int i = threadIdx.x; i < SCAN_CHUNK; i += 256) {
        int idx = base + i;
        sum += (idx < L) ? in[idx] : 0;
    }
    sdata[threadIdx.x] = sum;
    __syncthreads();
    for (int s = 128; s > 0; s >>= 1) {
        if (threadIdx.x < s) sdata[threadIdx.x] += sdata[threadIdx.x + s];
        __syncthreads();
    }
    if (threadIdx.x == 0) partials[blockIdx.x] = sdata[0];
}

__global__ void scan_partials_kernel(int* __restrict__ partials, int nb,
                                     int* __restrict__ out, int L) {
    if (threadIdx.x == 0 && blockIdx.x == 0) {
        int acc = 0;
        for (int i = 0; i < nb; i++) { int v = partials[i]; partials[i] = acc; acc += v; }
        out[L] = acc;  // total = E
    }
}

__global__ void scan_write_kernel(const int* __restrict__ in, const int* __restrict__ partials,
                                  int* __restrict__ out, int L) {
    __shared__ int sdata[256];
    int base = blockIdx.x * SCAN_CHUNK;
    int tbase = base + threadIdx.x * 4;
    int vals[4];
    int tsum = 0;
    #pragma unroll
    for (int j = 0; j < 4; j++) {
        int idx = tbase + j;
        vals[j] = (idx < L) ? in[idx] : 0;
        tsum += vals[j];
    }
    sdata[threadIdx.x] = tsum;
    __syncthreads();
    for (int s = 1; s < 256; s <<= 1) {
        int v = (threadIdx.x >= s) ? sdata[threadIdx.x - s] : 0;
        __syncthreads();
        sdata[threadIdx.x] += v;
        __syncthreads();
    }
    int excl = (threadIdx.x == 0) ? 0 : sdata[threadIdx.x - 1];
    int offset = partials[blockIdx.x] + excl;
    #pragma unroll
    for (int j = 0; j < 4; j++) {
        int idx = tbase + j;
        if (idx < L) out[idx] = offset;
        offset += vals[j];
    }
}

// ---------------- pass B: scatter packed (src|ldst<<24) into (bucket,chunk) windows ----------------

__global__ __launch_bounds__(HTHREADS) void chunk_scatter_kernel(const int* __restrict__ src,
                                                                 const int* __restrict__ dst,
                                                                 const int* __restrict__ histBase,
                                                                 int* __restrict__ binned,
                                                                 int E, int NB, int chunk) {
    __shared__ int cur[MAXNB];
    int c = blockIdx.x;
    for (int i = threadIdx.x; i < NB; i += HTHREADS) cur[i] = histBase[i * NCH + c];
    __syncthreads();
    int beg = c * chunk, end = min(beg + chunk, E);
    int e = beg + threadIdx.x * 4;
    for (; e + 4 <= end; e += HTHREADS * 4) {
        int4 s4 = *reinterpret_cast<const int4*>(&src[e]);
        int4 d4 = *reinterpret_cast<const int4*>(&dst[e]);
        int p0 = atomicAdd(&cur[d4.x >> BSHIFT], 1);
        binned[p0] = s4.x | ((d4.x & (BNODES - 1)) << 24);
        int p1 = atomicAdd(&cur[d4.y >> BSHIFT], 1);
        binned[p1] = s4.y | ((d4.y & (BNODES - 1)) << 24);
        int p2 = atomicAdd(&cur[d4.z >> BSHIFT], 1);
        binned[p2] = s4.z | ((d4.z & (BNODES - 1)) << 24);
        int p3 = atomicAdd(&cur[d4.w >> BSHIFT], 1);
        binned[p3] = s4.w | ((d4.w & (BNODES - 1)) << 24);
    }
    for (; e < end; ++e) {
        int s = src[e], d = dst[e];
        int pos = atomicAdd(&cur[d >> BSHIFT], 1);
        binned[pos] = s | ((d & (BNODES - 1)) << 24);
    }
}

// ---------------- fused per-bucket: node hist + local scan -> row_ptr/dinv + CSR scatter ----------------

__global__ __launch_bounds__(512) void bucket_finalize_kernel(const int* __restrict__ binned,
                                                              const int* __restrict__ histBase,
                                                              int* __restrict__ row_ptr,
                                                              float* __restrict__ dinv,
                                                              int* __restrict__ srcidx, int n) {
    __shared__ int cl[BNODES];   // counts, then cursors
    __shared__ int sl[BNODES];   // scan workspace
    int b = blockIdx.x;
    int tid = threadIdx.x;
    if (tid < BNODES) cl[tid] = 0;
    __syncthreads();
    int beg = histBase[b * NCH], end = histBase[(b + 1) * NCH];
    for (int e = beg + tid; e < end; e += 512)
        atomicAdd(&cl[(uint_t)binned[e] >> 24], 1);
    __syncthreads();
    int mycnt = (tid < BNODES) ? cl[tid] : 0;
    if (tid < BNODES) sl[tid] = mycnt;
    __syncthreads();
    for (int s = 1; s < 256; s <<= 1) {           // Hillis-Steele inclusive (tid<256 lanes)
        int v = (tid >= s && tid < BNODES) ? sl[tid - s] : 0;
        __syncthreads();
        if (tid < BNODES) sl[tid] += v;
        __syncthreads();
    }
    if (tid < BNODES) {
        int excl = tid ? sl[tid - 1] : 0;
        int myrp = beg + excl;
        cl[tid] = myrp;                           // becomes fill cursor
        int node = (b << BSHIFT) + tid;
        if (node < n) {
            row_ptr[node] = myrp;
            dinv[node] = rsqrtf((float)(mycnt + 1));  // +1 self-loop
            if (node == n - 1) row_ptr[n] = myrp + mycnt;
        }
    }
    __syncthreads();
    for (int e = beg + tid; e < end; e += 512) {  // binned slice is L2-hot from pass 1
        int v = binned[e];
        int pos = atomicAdd(&cl[(uint_t)v >> 24], 1);
        srcidx[pos] = v & 0xFFFFFF;
    }
}

// ---------------- dense transform: g[r][c] = bf16(dinv[r] * sum_k in[r][k]*W[k][c]) ----------------

__global__ __launch_bounds__(256) void transform_kernel(const float* __restrict__ in,
                                                        const float* __restrict__ W,
                                                        const float* __restrict__ dinv,
                                                        ushort_t* __restrict__ g, int n) {
    __shared__ float xs[4 * 256];                 // 4 waves/block x (4 rows x 64 floats)
    int lane = threadIdx.x & 63;
    int wslot = threadIdx.x >> 6;
    float* myxs = &xs[wslot * 256];

    float wreg[64];                               // W[k][lane] in VGPRs
    #pragma unroll
    for (int k = 0; k < 64; k++) wreg[k] = W[k * 64 + lane];

    int wave = (blockIdx.x * 256 + threadIdx.x) >> 6;
    int nwaves = gridDim.x * 4;
    int ngroups = (n + 3) >> 2;
    for (int grp = wave; grp < ngroups; grp += nwaves) {
        int r0 = grp * 4;
        if (r0 + 4 <= n) {
            float4 xv = *reinterpret_cast<const float4*>(&in[(size_t)r0 * 64 + lane * 4]);
            *reinterpret_cast<float4*>(&myxs[lane * 4]) = xv;
            float acc0 = 0.f, acc1 = 0.f, acc2 = 0.f, acc3 = 0.f;
            #pragma unroll
            for (int k4 = 0; k4 < 16; k4++) {
                float4 a = *reinterpret_cast<const float4*>(&myxs[0 * 64 + k4 * 4]);
                float4 b = *reinterpret_cast<const float4*>(&myxs[1 * 64 + k4 * 4]);
                float4 c = *reinterpret_cast<const float4*>(&myxs[2 * 64 + k4 * 4]);
                float4 d = *reinterpret_cast<const float4*>(&myxs[3 * 64 + k4 * 4]);
                float w0 = wreg[k4 * 4 + 0], w1 = wreg[k4 * 4 + 1];
                float w2 = wreg[k4 * 4 + 2], w3 = wreg[k4 * 4 + 3];
                acc0 = fmaf(a.x, w0, acc0); acc0 = fmaf(a.y, w1, acc0);
                acc0 = fmaf(a.z, w2, acc0); acc0 = fmaf(a.w, w3, acc0);
                acc1 = fmaf(b.x, w0, acc1); acc1 = fmaf(b.y, w1, acc1);
                acc1 = fmaf(b.z, w2, acc1); acc1 = fmaf(b.w, w3, acc1);
                acc2 = fmaf(c.x, w0, acc2); acc2 = fmaf(c.y, w1, acc2);
                acc2 = fmaf(c.z, w2, acc2); acc2 = fmaf(c.w, w3, acc2);
                acc3 = fmaf(d.x, w0, acc3); acc3 = fmaf(d.y, w1, acc3);
                acc3 = fmaf(d.z, w2, acc3); acc3 = fmaf(d.w, w3, acc3);
            }
            g[(size_t)(r0 + 0) * 64 + lane] = f32_to_bf16(acc0 * dinv[r0 + 0]);
            g[(size_t)(r0 + 1) * 64 + lane] = f32_to_bf16(acc1 * dinv[r0 + 1]);
            g[(size_t)(r0 + 2) * 64 + lane] = f32_to_bf16(acc2 * dinv[r0 + 2]);
            g[(size_t)(r0 + 3) * 64 + lane] = f32_to_bf16(acc3 * dinv[r0 + 3]);
        } else {
            for (int r = r0; r < n; r++) {
                float acc = 0.f;
                #pragma unroll
                for (int k = 0; k < 64; k++) acc = fmaf(in[(size_t)r * 64 + k], wreg[k], acc);
                g[(size_t)r * 64 + lane] = f32_to_bf16(acc * dinv[r]);
            }
        }
    }
}

// ---------------- aggregate: one wave per node, 16 gathers in flight (two sum trees) ----------------

__global__ __launch_bounds__(256) void aggregate_kernel(const ushort_t* __restrict__ g,
                                                        const int* __restrict__ row_ptr,
                                                        const int* __restrict__ srcidx,
                                                        const float* __restrict__ dinv,
                                                        const float* __restrict__ b,
                                                        float* __restrict__ out, int n, int relu) {
    int lane = threadIdx.x & 63;
    int node = (blockIdx.x * 256 + threadIdx.x) >> 6;
    if (node >= n) return;
    node = __builtin_amdgcn_readfirstlane(node);
    int beg = row_ptr[node];
    int end = row_ptr[node + 1];
    const ushort_t* gl = g + lane;
    float acc = bf16_to_f32(gl[(size_t)node * 64]);  // self-loop (g has dinv folded)
    int e = beg;
    for (; e + 16 <= end; e += 16) {
        int s0 = srcidx[e + 0],  s1 = srcidx[e + 1],  s2 = srcidx[e + 2],  s3 = srcidx[e + 3];
        int s4 = srcidx[e + 4],  s5 = srcidx[e + 5],  s6 = srcidx[e + 6],  s7 = srcidx[e + 7];
        int s8 = srcidx[e + 8],  s9 = srcidx[e + 9],  sa = srcidx[e + 10], sb = srcidx[e + 11];
        int sc = srcidx[e + 12], sd = srcidx[e + 13], se = srcidx[e + 14], sf = srcidx[e + 15];
        float v0 = bf16_to_f32(gl[(size_t)s0 * 64]);
        float v1 = bf16_to_f32(gl[(size_t)s1 * 64]);
        float v2 = bf16_to_f32(gl[(size_t)s2 * 64]);
        float v3 = bf16_to_f32(gl[(size_t)s3 * 64]);
        float v4 = bf16_to_f32(gl[(size_t)s4 * 64]);
        float v5 = bf16_to_f32(gl[(size_t)s5 * 64]);
        float v6 = bf16_to_f32(gl[(size_t)s6 * 64]);
        float v7 = bf16_to_f32(gl[(size_t)s7 * 64]);
        float v8 = bf16_to_f32(gl[(size_t)s8 * 64]);
        float v9 = bf16_to_f32(gl[(size_t)s9 * 64]);
        float va = bf16_to_f32(gl[(size_t)sa * 64]);
        float vb = bf16_to_f32(gl[(size_t)sb * 64]);
        float vc = bf16_to_f32(gl[(size_t)sc * 64]);
        float vd = bf16_to_f32(gl[(size_t)sd * 64]);
        float ve = bf16_to_f32(gl[(size_t)se * 64]);
        float vf = bf16_to_f32(gl[(size_t)sf * 64]);
        float t0 = ((v0 + v1) + (v2 + v3)) + ((v4 + v5) + (v6 + v7));
        float t1 = ((v8 + v9) + (va + vb)) + ((vc + vd) + (ve + vf));
        acc += t0 + t1;
    }
    for (; e + 4 <= end; e += 4) {
        int s0 = srcidx[e + 0], s1 = srcidx[e + 1], s2 = srcidx[e + 2], s3 = srcidx[e + 3];
        float v0 = bf16_to_f32(gl[(size_t)s0 * 64]);
        float v1 = bf16_to_f32(gl[(size_t)s1 * 64]);
        float v2 = bf16_to_f32(gl[(size_t)s2 * 64]);
        float v3 = bf16_to_f32(gl[(size_t)s3 * 64]);
        acc += (v0 + v1) + (v2 + v3);
    }
    for (; e < end; ++e) acc += bf16_to_f32(gl[(size_t)srcidx[e] * 64]);
    float o = fmaf(dinv[node], acc, b[lane]);
    out[(size_t)node * 64 + lane] = relu ? fmaxf(o, 0.f) : o;
}

extern "C" void kernel_launch(void* const* d_in, const int* in_sizes, int n_in,
                              void* d_out, int out_size, void* d_ws, size_t ws_size,
                              hipStream_t stream) {
    const float* x  = (const float*)d_in[0];
    const int*   ei = (const int*)d_in[1];
    const float* W1 = (const float*)d_in[2];
    const float* b1 = (const float*)d_in[3];
    const float* W2 = (const float*)d_in[4];
    const float* b2 = (const float*)d_in[5];
    float* out = (float*)d_out;

    const int n = in_sizes[0] / 64;      // 100000
    const int E = in_sizes[1] / 2;       // 3200000
    const int* src = ei;
    const int* dst = ei + E;
    const int NB = (n + BNODES - 1) >> BSHIFT;         // 391 buckets
    const int chunk = (E + NCH - 1) / NCH;             // 12500 edges/chunk
    const int L = NB * NCH;                            // histogram length

    // workspace carve-up (256B aligned)
    char* ws = (char*)d_ws;
    size_t off = 0;
    auto carve = [&](size_t bytes) { char* p = ws + off; off = (off + bytes + 255) & ~(size_t)255; return p; };
    int*      row_ptr  = (int*)     carve((size_t)(n + 1) * 4);
    int*      partials = (int*)     carve(4096);
    float*    dinv     = (float*)   carve((size_t)n * 4);
    int*      histG    = (int*)     carve((size_t)L * 4);
    int*      histBase = (int*)     carve((size_t)(L + 1) * 4);
    int*      srcidx   = (int*)     carve((size_t)E * 4);
    int*      binned   = (int*)     carve((size_t)E * 4);        // packed src|ldst<<24
    ushort_t* g        = (ushort_t*)carve((size_t)n * 64 * 2);   // bf16 scaled features

    const int nbs_hist = (L + SCAN_CHUNK - 1) / SCAN_CHUNK;

    // ---- CSR build via chunked two-pass radix partition (shared by both layers) ----
    chunk_hist_kernel<<<NCH, HTHREADS, 0, stream>>>(dst, histG, E, NB, chunk);
    block_sum_kernel<<<nbs_hist, 256, 0, stream>>>(histG, partials, L);
    scan_partials_kernel<<<1, 64, 0, stream>>>(partials, nbs_hist, histBase, L);
    scan_write_kernel<<<nbs_hist, 256, 0, stream>>>(histG, partials, histBase, L);
    chunk_scatter_kernel<<<NCH, HTHREADS, 0, stream>>>(src, dst, histBase, binned, E, NB, chunk);
    bucket_finalize_kernel<<<NB, 512, 0, stream>>>(binned, histBase, row_ptr, dinv, srcidx, n);

    const int agg_grid = (n * 64 + 255) / 256;   // one wave per node

    // ---- layer 1: g = bf16((x@W1)*dinv) ; h1 = relu(dinv*(agg(g)+g)+b1) -> d_out (f32) ----
    transform_kernel<<<2048, 256, 0, stream>>>(x, W1, dinv, g, n);
    aggregate_kernel<<<agg_grid, 256, 0, stream>>>(g, row_ptr, srcidx, dinv, b1, out, n, 1);

    // ---- layer 2: g = bf16((h1@W2)*dinv) ; out = dinv*(agg(g)+g)+b2 ----
    transform_kernel<<<2048, 256, 0, stream>>>(out, W2, dinv, g, n);
    aggregate_kernel<<<agg_grid, 256, 0, stream>>>(g, row_ptr, srcidx, dinv, b2, out, n, 0);
}

// Round 11
// 228.002 us; speedup vs baseline: 12.4554x; 1.0218x over previous
//
#include <hip/hip_runtime.h>

typedef unsigned short ushort_t;
typedef unsigned int uint_t;

#define SCAN_CHUNK 1024
#define NCH 256          // edge chunks (= pass-A/B grid)
#define HTHREADS 1024    // threads for chunk hist/scatter (16 waves/CU)
#define BSHIFT 8
#define BNODES 256       // nodes per bucket
#define MAXNB 512        // max buckets (n <= 131072)

__device__ __forceinline__ ushort_t f32_to_bf16(float f) {
    uint_t u = __float_as_uint(f);
    return (ushort_t)((u + 0x7FFF + ((u >> 16) & 1)) >> 16);  // RNE
}
__device__ __forceinline__ float bf16_to_f32(ushort_t h) {
    return __uint_as_float((uint_t)h << 16);
}

// ---------------- pass A: per-chunk bucket histogram ----------------

__global__ __launch_bounds__(HTHREADS) void chunk_hist_kernel(const int* __restrict__ dst,
                                                              int* __restrict__ histG,
                                                              int E, int NB, int chunk) {
    __shared__ int lh[MAXNB];
    int c = blockIdx.x;
    for (int i = threadIdx.x; i < NB; i += HTHREADS) lh[i] = 0;
    __syncthreads();
    int beg = c * chunk, end = min(beg + chunk, E);
    int e = beg + threadIdx.x * 4;
    for (; e + 4 <= end; e += HTHREADS * 4) {
        int4 d4 = *reinterpret_cast<const int4*>(&dst[e]);
        atomicAdd(&lh[d4.x >> BSHIFT], 1);
        atomicAdd(&lh[d4.y >> BSHIFT], 1);
        atomicAdd(&lh[d4.z >> BSHIFT], 1);
        atomicAdd(&lh[d4.w >> BSHIFT], 1);
    }
    for (; e < end; ++e) atomicAdd(&lh[dst[e] >> BSHIFT], 1);
    __syncthreads();
    for (int i = threadIdx.x; i < NB; i += HTHREADS) histG[i * NCH + c] = lh[i];  // bucket-major
}

// ---------------- 3-kernel exclusive scan of histG (L entries) ----------------

__global__ void block_sum_kernel(const int* __restrict__ in, int* __restrict__ partials, int L) {
    __shared__ int sdata[256];
    int base = blockIdx.x * SCAN_CHUNK;
    int sum = 0;
    for (int i = threadIdx.x; i < SCAN_CHUNK; i += 256) {
        int idx = base + i;
        sum += (idx < L) ? in[idx] : 0;
    }
    sdata[threadIdx.x] = sum;
    __syncthreads();
    for (int s = 128; s > 0; s >>= 1) {
        if (threadIdx.x < s) sdata[threadIdx.x] += sdata[threadIdx.x + s];
        __syncthreads();
    }
    if (threadIdx.x == 0) partials[blockIdx.x] = sdata[0];
}

// parallel exclusive scan of partials (nb <= 256) in one 256-thread block
__global__ __launch_bounds__(256) void scan_partials_kernel(int* __restrict__ partials, int nb,
                                                            int* __restrict__ out, int L) {
    __shared__ int s[256];
    int tid = threadIdx.x;
    int v = (tid < nb) ? partials[tid] : 0;
    s[tid] = v;
    __syncthreads();
    for (int d = 1; d < 256; d <<= 1) {
        int t = (tid >= d) ? s[tid - d] : 0;
        __syncthreads();
        s[tid] += t;
        __syncthreads();
    }
    if (tid < nb) partials[tid] = s[tid] - v;   // exclusive
    if (tid == 255) out[L] = s[255];            // total = E
}

__global__ void scan_write_kernel(const int* __restrict__ in, const int* __restrict__ partials,
                                  int* __restrict__ out, int L) {
    __shared__ int sdata[256];
    int base = blockIdx.x * SCAN_CHUNK;
    int tbase = base + threadIdx.x * 4;
    int vals[4];
    int tsum = 0;
    #pragma unroll
    for (int j = 0; j < 4; j++) {
        int idx = tbase + j;
        vals[j] = (idx < L) ? in[idx] : 0;
        tsum += vals[j];
    }
    sdata[threadIdx.x] = tsum;
    __syncthreads();
    for (int s = 1; s < 256; s <<= 1) {
        int v = (threadIdx.x >= s) ? sdata[threadIdx.x - s] : 0;
        __syncthreads();
        sdata[threadIdx.x] += v;
        __syncthreads();
    }
    int excl = (threadIdx.x == 0) ? 0 : sdata[threadIdx.x - 1];
    int offset = partials[blockIdx.x] + excl;
    #pragma unroll
    for (int j = 0; j < 4; j++) {
        int idx = tbase + j;
        if (idx < L) out[idx] = offset;
        offset += vals[j];
    }
}

// ---------------- pass B: scatter packed (src|ldst<<24) into (bucket,chunk) windows ----------------

__global__ __launch_bounds__(HTHREADS) void chunk_scatter_kernel(const int* __restrict__ src,
                                                                 const int* __restrict__ dst,
                                                                 const int* __restrict__ histBase,
                                                                 int* __restrict__ binned,
                                                                 int E, int NB, int chunk) {
    __shared__ int cur[MAXNB];
    int c = blockIdx.x;
    for (int i = threadIdx.x; i < NB; i += HTHREADS) cur[i] = histBase[i * NCH + c];
    __syncthreads();
    int beg = c * chunk, end = min(beg + chunk, E);
    int e = beg + threadIdx.x * 4;
    for (; e + 4 <= end; e += HTHREADS * 4) {
        int4 s4 = *reinterpret_cast<const int4*>(&src[e]);
        int4 d4 = *reinterpret_cast<const int4*>(&dst[e]);
        int p0 = atomicAdd(&cur[d4.x >> BSHIFT], 1);
        binned[p0] = s4.x | ((d4.x & (BNODES - 1)) << 24);
        int p1 = atomicAdd(&cur[d4.y >> BSHIFT], 1);
        binned[p1] = s4.y | ((d4.y & (BNODES - 1)) << 24);
        int p2 = atomicAdd(&cur[d4.z >> BSHIFT], 1);
        binned[p2] = s4.z | ((d4.z & (BNODES - 1)) << 24);
        int p3 = atomicAdd(&cur[d4.w >> BSHIFT], 1);
        binned[p3] = s4.w | ((d4.w & (BNODES - 1)) << 24);
    }
    for (; e < end; ++e) {
        int s = src[e], d = dst[e];
        int pos = atomicAdd(&cur[d >> BSHIFT], 1);
        binned[pos] = s | ((d & (BNODES - 1)) << 24);
    }
}

// ---------------- fused per-bucket: node hist + local scan -> row_ptr/dinv + CSR scatter ----------------

__global__ __launch_bounds__(512) void bucket_finalize_kernel(const int* __restrict__ binned,
                                                              const int* __restrict__ histBase,
                                                              int* __restrict__ row_ptr,
                                                              float* __restrict__ dinv,
                                                              int* __restrict__ srcidx, int n) {
    __shared__ int cl[BNODES];   // counts, then cursors
    __shared__ int sl[BNODES];   // scan workspace
    int b = blockIdx.x;
    int tid = threadIdx.x;
    if (tid < BNODES) cl[tid] = 0;
    __syncthreads();
    int beg = histBase[b * NCH], end = histBase[(b + 1) * NCH];
    for (int e = beg + tid; e < end; e += 512)
        atomicAdd(&cl[(uint_t)binned[e] >> 24], 1);
    __syncthreads();
    int mycnt = (tid < BNODES) ? cl[tid] : 0;
    if (tid < BNODES) sl[tid] = mycnt;
    __syncthreads();
    for (int s = 1; s < 256; s <<= 1) {           // Hillis-Steele inclusive (tid<256 lanes)
        int v = (tid >= s && tid < BNODES) ? sl[tid - s] : 0;
        __syncthreads();
        if (tid < BNODES) sl[tid] += v;
        __syncthreads();
    }
    if (tid < BNODES) {
        int excl = tid ? sl[tid - 1] : 0;
        int myrp = beg + excl;
        cl[tid] = myrp;                           // becomes fill cursor
        int node = (b << BSHIFT) + tid;
        if (node < n) {
            row_ptr[node] = myrp;
            dinv[node] = rsqrtf((float)(mycnt + 1));  // +1 self-loop
            if (node == n - 1) row_ptr[n] = myrp + mycnt;
        }
    }
    __syncthreads();
    for (int e = beg + tid; e < end; e += 512) {  // binned slice is L2-hot from pass 1
        int v = binned[e];
        int pos = atomicAdd(&cl[(uint_t)v >> 24], 1);
        srcidx[pos] = v & 0xFFFFFF;
    }
}

// ---------------- dense transform: g[r][c] = bf16(dinv[r] * sum_k in[r][k]*W[k][c]) ----------------

__global__ __launch_bounds__(256) void transform_kernel(const float* __restrict__ in,
                                                        const float* __restrict__ W,
                                                        const float* __restrict__ dinv,
                                                        ushort_t* __restrict__ g, int n) {
    __shared__ float xs[4 * 256];                 // 4 waves/block x (4 rows x 64 floats)
    int lane = threadIdx.x & 63;
    int wslot = threadIdx.x >> 6;
    float* myxs = &xs[wslot * 256];

    float wreg[64];                               // W[k][lane] in VGPRs
    #pragma unroll
    for (int k = 0; k < 64; k++) wreg[k] = W[k * 64 + lane];

    int wave = (blockIdx.x * 256 + threadIdx.x) >> 6;
    int nwaves = gridDim.x * 4;
    int ngroups = (n + 3) >> 2;
    for (int grp = wave; grp < ngroups; grp += nwaves) {
        int r0 = grp * 4;
        if (r0 + 4 <= n) {
            float4 xv = *reinterpret_cast<const float4*>(&in[(size_t)r0 * 64 + lane * 4]);
            *reinterpret_cast<float4*>(&myxs[lane * 4]) = xv;
            float acc0 = 0.f, acc1 = 0.f, acc2 = 0.f, acc3 = 0.f;
            #pragma unroll
            for (int k4 = 0; k4 < 16; k4++) {
                float4 a = *reinterpret_cast<const float4*>(&myxs[0 * 64 + k4 * 4]);
                float4 b = *reinterpret_cast<const float4*>(&myxs[1 * 64 + k4 * 4]);
                float4 c = *reinterpret_cast<const float4*>(&myxs[2 * 64 + k4 * 4]);
                float4 d = *reinterpret_cast<const float4*>(&myxs[3 * 64 + k4 * 4]);
                float w0 = wreg[k4 * 4 + 0], w1 = wreg[k4 * 4 + 1];
                float w2 = wreg[k4 * 4 + 2], w3 = wreg[k4 * 4 + 3];
                acc0 = fmaf(a.x, w0, acc0); acc0 = fmaf(a.y, w1, acc0);
                acc0 = fmaf(a.z, w2, acc0); acc0 = fmaf(a.w, w3, acc0);
                acc1 = fmaf(b.x, w0, acc1); acc1 = fmaf(b.y, w1, acc1);
                acc1 = fmaf(b.z, w2, acc1); acc1 = fmaf(b.w, w3, acc1);
                acc2 = fmaf(c.x, w0, acc2); acc2 = fmaf(c.y, w1, acc2);
                acc2 = fmaf(c.z, w2, acc2); acc2 = fmaf(c.w, w3, acc2);
                acc3 = fmaf(d.x, w0, acc3); acc3 = fmaf(d.y, w1, acc3);
                acc3 = fmaf(d.z, w2, acc3); acc3 = fmaf(d.w, w3, acc3);
            }
            g[(size_t)(r0 + 0) * 64 + lane] = f32_to_bf16(acc0 * dinv[r0 + 0]);
            g[(size_t)(r0 + 1) * 64 + lane] = f32_to_bf16(acc1 * dinv[r0 + 1]);
            g[(size_t)(r0 + 2) * 64 + lane] = f32_to_bf16(acc2 * dinv[r0 + 2]);
            g[(size_t)(r0 + 3) * 64 + lane] = f32_to_bf16(acc3 * dinv[r0 + 3]);
        } else {
            for (int r = r0; r < n; r++) {
                float acc = 0.f;
                #pragma unroll
                for (int k = 0; k < 64; k++) acc = fmaf(in[(size_t)r * 64 + k], wreg[k], acc);
                g[(size_t)r * 64 + lane] = f32_to_bf16(acc * dinv[r]);
            }
        }
    }
}

// ---------------- aggregate: one wave per node; full blocks unmasked, ONE clamped+masked tail ----------------

__global__ __launch_bounds__(256) void aggregate_kernel(const ushort_t* __restrict__ g,
                                                        const int* __restrict__ row_ptr,
                                                        const int* __restrict__ srcidx,
                                                        const float* __restrict__ dinv,
                                                        const float* __restrict__ b,
                                                        float* __restrict__ out, int n, int relu) {
    int lane = threadIdx.x & 63;
    int node = (blockIdx.x * 256 + threadIdx.x) >> 6;
    if (node >= n) return;
    node = __builtin_amdgcn_readfirstlane(node);
    int beg = row_ptr[node];
    int end = row_ptr[node + 1];
    const ushort_t* gl = g + lane;
    float acc = bf16_to_f32(gl[(size_t)node * 64]);  // self-loop (g has dinv folded)
    int e = beg;
    for (; e + 16 <= end; e += 16) {                 // fast path: full 16-blocks
        int s0 = srcidx[e + 0],  s1 = srcidx[e + 1],  s2 = srcidx[e + 2],  s3 = srcidx[e + 3];
        int s4 = srcidx[e + 4],  s5 = srcidx[e + 5],  s6 = srcidx[e + 6],  s7 = srcidx[e + 7];
        int s8 = srcidx[e + 8],  s9 = srcidx[e + 9],  sa = srcidx[e + 10], sb = srcidx[e + 11];
        int sc = srcidx[e + 12], sd = srcidx[e + 13], se = srcidx[e + 14], sf = srcidx[e + 15];
        float v0 = bf16_to_f32(gl[(size_t)s0 * 64]);
        float v1 = bf16_to_f32(gl[(size_t)s1 * 64]);
        float v2 = bf16_to_f32(gl[(size_t)s2 * 64]);
        float v3 = bf16_to_f32(gl[(size_t)s3 * 64]);
        float v4 = bf16_to_f32(gl[(size_t)s4 * 64]);
        float v5 = bf16_to_f32(gl[(size_t)s5 * 64]);
        float v6 = bf16_to_f32(gl[(size_t)s6 * 64]);
        float v7 = bf16_to_f32(gl[(size_t)s7 * 64]);
        float v8 = bf16_to_f32(gl[(size_t)s8 * 64]);
        float v9 = bf16_to_f32(gl[(size_t)s9 * 64]);
        float va = bf16_to_f32(gl[(size_t)sa * 64]);
        float vb = bf16_to_f32(gl[(size_t)sb * 64]);
        float vc = bf16_to_f32(gl[(size_t)sc * 64]);
        float vd = bf16_to_f32(gl[(size_t)sd * 64]);
        float ve = bf16_to_f32(gl[(size_t)se * 64]);
        float vf = bf16_to_f32(gl[(size_t)sf * 64]);
        float t0 = ((v0 + v1) + (v2 + v3)) + ((v4 + v5) + (v6 + v7));
        float t1 = ((v8 + v9) + (va + vb)) + ((vc + vd) + (ve + vf));
        acc += t0 + t1;
    }
    if (e < end) {                                   // tail: one clamped, masked 16-block
        int last = end - 1;
        int i1 = min(e + 1, last),  i2 = min(e + 2, last),  i3 = min(e + 3, last);
        int i4 = min(e + 4, last),  i5 = min(e + 5, last),  i6 = min(e + 6, last);
        int i7 = min(e + 7, last),  i8 = min(e + 8, last),  i9 = min(e + 9, last);
        int ia = min(e + 10, last), ib = min(e + 11, last), ic = min(e + 12, last);
        int id = min(e + 13, last), ie = min(e + 14, last), if_ = min(e + 15, last);
        int s0 = srcidx[e],  s1 = srcidx[i1], s2 = srcidx[i2], s3 = srcidx[i3];
        int s4 = srcidx[i4], s5 = srcidx[i5], s6 = srcidx[i6], s7 = srcidx[i7];
        int s8 = srcidx[i8], s9 = srcidx[i9], sa = srcidx[ia], sb = srcidx[ib];
        int sc = srcidx[ic], sd = srcidx[id], se = srcidx[ie], sf = srcidx[if_];
        float v0 = bf16_to_f32(gl[(size_t)s0 * 64]);
        float v1 = bf16_to_f32(gl[(size_t)s1 * 64]);
        float v2 = bf16_to_f32(gl[(size_t)s2 * 64]);
        float v3 = bf16_to_f32(gl[(size_t)s3 * 64]);
        float v4 = bf16_to_f32(gl[(size_t)s4 * 64]);
        float v5 = bf16_to_f32(gl[(size_t)s5 * 64]);
        float v6 = bf16_to_f32(gl[(size_t)s6 * 64]);
        float v7 = bf16_to_f32(gl[(size_t)s7 * 64]);
        float v8 = bf16_to_f32(gl[(size_t)s8 * 64]);
        float v9 = bf16_to_f32(gl[(size_t)s9 * 64]);
        float va = bf16_to_f32(gl[(size_t)sa * 64]);
        float vb = bf16_to_f32(gl[(size_t)sb * 64]);
        float vc = bf16_to_f32(gl[(size_t)sc * 64]);
        float vd = bf16_to_f32(gl[(size_t)sd * 64]);
        float ve = bf16_to_f32(gl[(size_t)se * 64]);
        float vf = bf16_to_f32(gl[(size_t)sf * 64]);
        v1 = (e + 1 < end) ? v1 : 0.f;   v2 = (e + 2 < end) ? v2 : 0.f;
        v3 = (e + 3 < end) ? v3 : 0.f;   v4 = (e + 4 < end) ? v4 : 0.f;
        v5 = (e + 5 < end) ? v5 : 0.f;   v6 = (e + 6 < end) ? v6 : 0.f;
        v7 = (e + 7 < end) ? v7 : 0.f;   v8 = (e + 8 < end) ? v8 : 0.f;
        v9 = (e + 9 < end) ? v9 : 0.f;   va = (e + 10 < end) ? va : 0.f;
        vb = (e + 11 < end) ? vb : 0.f;  vc = (e + 12 < end) ? vc : 0.f;
        vd = (e + 13 < end) ? vd : 0.f;  ve = (e + 14 < end) ? ve : 0.f;
        vf = (e + 15 < end) ? vf : 0.f;
        float t0 = ((v0 + v1) + (v2 + v3)) + ((v4 + v5) + (v6 + v7));
        float t1 = ((v8 + v9) + (va + vb)) + ((vc + vd) + (ve + vf));
        acc += t0 + t1;
    }
    float o = fmaf(dinv[node], acc, b[lane]);
    out[(size_t)node * 64 + lane] = relu ? fmaxf(o, 0.f) : o;
}

extern "C" void kernel_launch(void* const* d_in, const int* in_sizes, int n_in,
                              void* d_out, int out_size, void* d_ws, size_t ws_size,
                              hipStream_t stream) {
    const float* x  = (const float*)d_in[0];
    const int*   ei = (const int*)d_in[1];
    const float* W1 = (const float*)d_in[2];
    const float* b1 = (const float*)d_in[3];
    const float* W2 = (const float*)d_in[4];
    const float* b2 = (const float*)d_in[5];
    float* out = (float*)d_out;

    const int n = in_sizes[0] / 64;      // 100000
    const int E = in_sizes[1] / 2;       // 3200000
    const int* src = ei;
    const int* dst = ei + E;
    const int NB = (n + BNODES - 1) >> BSHIFT;         // 391 buckets
    const int chunk = (E + NCH - 1) / NCH;             // 12500 edges/chunk
    const int L = NB * NCH;                            // histogram length

    // workspace carve-up (256B aligned)
    char* ws = (char*)d_ws;
    size_t off = 0;
    auto carve = [&](size_t bytes) { char* p = ws + off; off = (off + bytes + 255) & ~(size_t)255; return p; };
    int*      row_ptr  = (int*)     carve((size_t)(n + 1) * 4);
    int*      partials = (int*)     carve(4096);
    float*    dinv     = (float*)   carve((size_t)n * 4);
    int*      histG    = (int*)     carve((size_t)L * 4);
    int*      histBase = (int*)     carve((size_t)(L + 1) * 4);
    int*      srcidx   = (int*)     carve((size_t)E * 4);
    int*      binned   = (int*)     carve((size_t)E * 4);        // packed src|ldst<<24
    ushort_t* g        = (ushort_t*)carve((size_t)n * 64 * 2);   // bf16 scaled features

    const int nbs_hist = (L + SCAN_CHUNK - 1) / SCAN_CHUNK;      // 98 <= 256

    // ---- CSR build via chunked two-pass radix partition (shared by both layers) ----
    chunk_hist_kernel<<<NCH, HTHREADS, 0, stream>>>(dst, histG, E, NB, chunk);
    block_sum_kernel<<<nbs_hist, 256, 0, stream>>>(histG, partials, L);
    scan_partials_kernel<<<1, 256, 0, stream>>>(partials, nbs_hist, histBase, L);
    scan_write_kernel<<<nbs_hist, 256, 0, stream>>>(histG, partials, histBase, L);
    chunk_scatter_kernel<<<NCH, HTHREADS, 0, stream>>>(src, dst, histBase, binned, E, NB, chunk);
    bucket_finalize_kernel<<<NB, 512, 0, stream>>>(binned, histBase, row_ptr, dinv, srcidx, n);

    const int agg_grid = (n * 64 + 255) / 256;   // one wave per node

    // ---- layer 1: g = bf16((x@W1)*dinv) ; h1 = relu(dinv*(agg(g)+g)+b1) -> d_out (f32) ----
    transform_kernel<<<2048, 256, 0, stream>>>(x, W1, dinv, g, n);
    aggregate_kernel<<<agg_grid, 256, 0, stream>>>(g, row_ptr, srcidx, dinv, b1, out, n, 1);

    // ---- layer 2: g = bf16((h1@W2)*dinv) ; out = dinv*(agg(g)+g)+b2 ----
    transform_kernel<<<2048, 256, 0, stream>>>(out, W2, dinv, g, n);
    aggregate_kernel<<<agg_grid, 256, 0, stream>>>(g, row_ptr, srcidx, dinv, b2, out, n, 0);
}

// Round 12
// 224.342 us; speedup vs baseline: 12.6586x; 1.0163x over previous
//
#include <hip/hip_runtime.h>

typedef unsigned short ushort_t;
typedef unsigned int uint_t;

#define SCAN_CHUNK 1024
#define NCH 256          // edge chunks (= pass-A/B grid)
#define HTHREADS 1024    // threads for chunk hist/scatter (16 waves/CU)
#define BSHIFT 8
#define BNODES 256       // nodes per bucket
#define MAXNB 512        // max buckets (n <= 131072)

__device__ __forceinline__ ushort_t f32_to_bf16(float f) {
    uint_t u = __float_as_uint(f);
    return (ushort_t)((u + 0x7FFF + ((u >> 16) & 1)) >> 16);  // RNE
}
__device__ __forceinline__ float bf16_to_f32(ushort_t h) {
    return __uint_as_float((uint_t)h << 16);
}

// ---------------- pass A: per-chunk bucket histogram ----------------

__global__ __launch_bounds__(HTHREADS) void chunk_hist_kernel(const int* __restrict__ dst,
                                                              int* __restrict__ histG,
                                                              int E, int NB, int chunk) {
    __shared__ int lh[MAXNB];
    int c = blockIdx.x;
    for (int i = threadIdx.x; i < NB; i += HTHREADS) lh[i] = 0;
    __syncthreads();
    int beg = c * chunk, end = min(beg + chunk, E);
    int e = beg + threadIdx.x * 4;
    for (; e + 4 <= end; e += HTHREADS * 4) {
        int4 d4 = *reinterpret_cast<const int4*>(&dst[e]);
        atomicAdd(&lh[d4.x >> BSHIFT], 1);
        atomicAdd(&lh[d4.y >> BSHIFT], 1);
        atomicAdd(&lh[d4.z >> BSHIFT], 1);
        atomicAdd(&lh[d4.w >> BSHIFT], 1);
    }
    for (; e < end; ++e) atomicAdd(&lh[dst[e] >> BSHIFT], 1);
    __syncthreads();
    for (int i = threadIdx.x; i < NB; i += HTHREADS) histG[i * NCH + c] = lh[i];  // bucket-major
}

// ---------------- 3-kernel exclusive scan of histG (L entries) ----------------

__global__ void block_sum_kernel(const int* __restrict__ in, int* __restrict__ partials, int L) {
    __shared__ int sdata[256];
    int base = blockIdx.x * SCAN_CHUNK;
    int sum = 0;
    for (int i = threadIdx.x; i < SCAN_CHUNK; i += 256) {
        int idx = base + i;
        sum += (idx < L) ? in[idx] : 0;
    }
    sdata[threadIdx.x] = sum;
    __syncthreads();
    for (int s = 128; s > 0; s >>= 1) {
        if (threadIdx.x < s) sdata[threadIdx.x] += sdata[threadIdx.x + s];
        __syncthreads();
    }
    if (threadIdx.x == 0) partials[blockIdx.x] = sdata[0];
}

// parallel exclusive scan of partials (nb <= 256) in one 256-thread block
__global__ __launch_bounds__(256) void scan_partials_kernel(int* __restrict__ partials, int nb,
                                                            int* __restrict__ out, int L) {
    __shared__ int s[256];
    int tid = threadIdx.x;
    int v = (tid < nb) ? partials[tid] : 0;
    s[tid] = v;
    __syncthreads();
    for (int d = 1; d < 256; d <<= 1) {
        int t = (tid >= d) ? s[tid - d] : 0;
        __syncthreads();
        s[tid] += t;
        __syncthreads();
    }
    if (tid < nb) partials[tid] = s[tid] - v;   // exclusive
    if (tid == 255) out[L] = s[255];            // total = E
}

__global__ void scan_write_kernel(const int* __restrict__ in, const int* __restrict__ partials,
                                  int* __restrict__ out, int L) {
    __shared__ int sdata[256];
    int base = blockIdx.x * SCAN_CHUNK;
    int tbase = base + threadIdx.x * 4;
    int vals[4];
    int tsum = 0;
    #pragma unroll
    for (int j = 0; j < 4; j++) {
        int idx = tbase + j;
        vals[j] = (idx < L) ? in[idx] : 0;
        tsum += vals[j];
    }
    sdata[threadIdx.x] = tsum;
    __syncthreads();
    for (int s = 1; s < 256; s <<= 1) {
        int v = (threadIdx.x >= s) ? sdata[threadIdx.x - s] : 0;
        __syncthreads();
        sdata[threadIdx.x] += v;
        __syncthreads();
    }
    int excl = (threadIdx.x == 0) ? 0 : sdata[threadIdx.x - 1];
    int offset = partials[blockIdx.x] + excl;
    #pragma unroll
    for (int j = 0; j < 4; j++) {
        int idx = tbase + j;
        if (idx < L) out[idx] = offset;
        offset += vals[j];
    }
}

// ---------------- pass B: scatter packed (src|ldst<<24) into (bucket,chunk) windows ----------------

__global__ __launch_bounds__(HTHREADS) void chunk_scatter_kernel(const int* __restrict__ src,
                                                                 const int* __restrict__ dst,
                                                                 const int* __restrict__ histBase,
                                                                 int* __restrict__ binned,
                                                                 int E, int NB, int chunk) {
    __shared__ int cur[MAXNB];
    int c = blockIdx.x;
    for (int i = threadIdx.x; i < NB; i += HTHREADS) cur[i] = histBase[i * NCH + c];
    __syncthreads();
    int beg = c * chunk, end = min(beg + chunk, E);
    int e = beg + threadIdx.x * 4;
    for (; e + 4 <= end; e += HTHREADS * 4) {
        int4 s4 = *reinterpret_cast<const int4*>(&src[e]);
        int4 d4 = *reinterpret_cast<const int4*>(&dst[e]);
        int p0 = atomicAdd(&cur[d4.x >> BSHIFT], 1);
        binned[p0] = s4.x | ((d4.x & (BNODES - 1)) << 24);
        int p1 = atomicAdd(&cur[d4.y >> BSHIFT], 1);
        binned[p1] = s4.y | ((d4.y & (BNODES - 1)) << 24);
        int p2 = atomicAdd(&cur[d4.z >> BSHIFT], 1);
        binned[p2] = s4.z | ((d4.z & (BNODES - 1)) << 24);
        int p3 = atomicAdd(&cur[d4.w >> BSHIFT], 1);
        binned[p3] = s4.w | ((d4.w & (BNODES - 1)) << 24);
    }
    for (; e < end; ++e) {
        int s = src[e], d = dst[e];
        int pos = atomicAdd(&cur[d >> BSHIFT], 1);
        binned[pos] = s | ((d & (BNODES - 1)) << 24);
    }
}

// ---------------- fused per-bucket: node hist + local scan -> row_ptr/dinv + CSR scatter ----------------

__global__ __launch_bounds__(512) void bucket_finalize_kernel(const int* __restrict__ binned,
                                                              const int* __restrict__ histBase,
                                                              int* __restrict__ row_ptr,
                                                              float* __restrict__ dinv,
                                                              int* __restrict__ srcidx, int n) {
    __shared__ int cl[BNODES];   // counts, then cursors
    __shared__ int sl[BNODES];   // scan workspace
    int b = blockIdx.x;
    int tid = threadIdx.x;
    if (tid < BNODES) cl[tid] = 0;
    __syncthreads();
    int beg = histBase[b * NCH], end = histBase[(b + 1) * NCH];
    for (int e = beg + tid; e < end; e += 512)
        atomicAdd(&cl[(uint_t)binned[e] >> 24], 1);
    __syncthreads();
    int mycnt = (tid < BNODES) ? cl[tid] : 0;
    if (tid < BNODES) sl[tid] = mycnt;
    __syncthreads();
    for (int s = 1; s < 256; s <<= 1) {           // Hillis-Steele inclusive (tid<256 lanes)
        int v = (tid >= s && tid < BNODES) ? sl[tid - s] : 0;
        __syncthreads();
        if (tid < BNODES) sl[tid] += v;
        __syncthreads();
    }
    if (tid < BNODES) {
        int excl = tid ? sl[tid - 1] : 0;
        int myrp = beg + excl;
        cl[tid] = myrp;                           // becomes fill cursor
        int node = (b << BSHIFT) + tid;
        if (node < n) {
            row_ptr[node] = myrp;
            dinv[node] = rsqrtf((float)(mycnt + 1));  // +1 self-loop
            if (node == n - 1) row_ptr[n] = myrp + mycnt;
        }
    }
    __syncthreads();
    for (int e = beg + tid; e < end; e += 512) {  // binned slice is L2-hot from pass 1
        int v = binned[e];
        int pos = atomicAdd(&cl[(uint_t)v >> 24], 1);
        srcidx[pos] = v & 0xFFFFFF;
    }
}

// ---------------- dense transform: g[r][c] = bf16(dinv[r] * sum_k in[r][k]*W[k][c]) ----------------

__global__ __launch_bounds__(256) void transform_kernel(const float* __restrict__ in,
                                                        const float* __restrict__ W,
                                                        const float* __restrict__ dinv,
                                                        ushort_t* __restrict__ g, int n) {
    __shared__ float xs[4 * 256];                 // 4 waves/block x (4 rows x 64 floats)
    int lane = threadIdx.x & 63;
    int wslot = threadIdx.x >> 6;
    float* myxs = &xs[wslot * 256];

    float wreg[64];                               // W[k][lane] in VGPRs
    #pragma unroll
    for (int k = 0; k < 64; k++) wreg[k] = W[k * 64 + lane];

    int wave = (blockIdx.x * 256 + threadIdx.x) >> 6;
    int nwaves = gridDim.x * 4;
    int ngroups = (n + 3) >> 2;
    for (int grp = wave; grp < ngroups; grp += nwaves) {
        int r0 = grp * 4;
        if (r0 + 4 <= n) {
            float4 xv = *reinterpret_cast<const float4*>(&in[(size_t)r0 * 64 + lane * 4]);
            *reinterpret_cast<float4*>(&myxs[lane * 4]) = xv;
            float acc0 = 0.f, acc1 = 0.f, acc2 = 0.f, acc3 = 0.f;
            #pragma unroll
            for (int k4 = 0; k4 < 16; k4++) {
                float4 a = *reinterpret_cast<const float4*>(&myxs[0 * 64 + k4 * 4]);
                float4 b = *reinterpret_cast<const float4*>(&myxs[1 * 64 + k4 * 4]);
                float4 c = *reinterpret_cast<const float4*>(&myxs[2 * 64 + k4 * 4]);
                float4 d = *reinterpret_cast<const float4*>(&myxs[3 * 64 + k4 * 4]);
                float w0 = wreg[k4 * 4 + 0], w1 = wreg[k4 * 4 + 1];
                float w2 = wreg[k4 * 4 + 2], w3 = wreg[k4 * 4 + 3];
                acc0 = fmaf(a.x, w0, acc0); acc0 = fmaf(a.y, w1, acc0);
                acc0 = fmaf(a.z, w2, acc0); acc0 = fmaf(a.w, w3, acc0);
                acc1 = fmaf(b.x, w0, acc1); acc1 = fmaf(b.y, w1, acc1);
                acc1 = fmaf(b.z, w2, acc1); acc1 = fmaf(b.w, w3, acc1);
                acc2 = fmaf(c.x, w0, acc2); acc2 = fmaf(c.y, w1, acc2);
                acc2 = fmaf(c.z, w2, acc2); acc2 = fmaf(c.w, w3, acc2);
                acc3 = fmaf(d.x, w0, acc3); acc3 = fmaf(d.y, w1, acc3);
                acc3 = fmaf(d.z, w2, acc3); acc3 = fmaf(d.w, w3, acc3);
            }
            g[(size_t)(r0 + 0) * 64 + lane] = f32_to_bf16(acc0 * dinv[r0 + 0]);
            g[(size_t)(r0 + 1) * 64 + lane] = f32_to_bf16(acc1 * dinv[r0 + 1]);
            g[(size_t)(r0 + 2) * 64 + lane] = f32_to_bf16(acc2 * dinv[r0 + 2]);
            g[(size_t)(r0 + 3) * 64 + lane] = f32_to_bf16(acc3 * dinv[r0 + 3]);
        } else {
            for (int r = r0; r < n; r++) {
                float acc = 0.f;
                #pragma unroll
                for (int k = 0; k < 64; k++) acc = fmaf(in[(size_t)r * 64 + k], wreg[k], acc);
                g[(size_t)r * 64 + lane] = f32_to_bf16(acc * dinv[r]);
            }
        }
    }
}

// ---------------- aggregate: one wave per node, 16 gathers in flight (two sum trees) ----------------

__global__ __launch_bounds__(256) void aggregate_kernel(const ushort_t* __restrict__ g,
                                                        const int* __restrict__ row_ptr,
                                                        const int* __restrict__ srcidx,
                                                        const float* __restrict__ dinv,
                                                        const float* __restrict__ b,
                                                        float* __restrict__ out, int n, int relu) {
    int lane = threadIdx.x & 63;
    int node = (blockIdx.x * 256 + threadIdx.x) >> 6;
    if (node >= n) return;
    node = __builtin_amdgcn_readfirstlane(node);
    int beg = row_ptr[node];
    int end = row_ptr[node + 1];
    const ushort_t* gl = g + lane;
    float acc = bf16_to_f32(gl[(size_t)node * 64]);  // self-loop (g has dinv folded)
    int e = beg;
    for (; e + 16 <= end; e += 16) {
        int s0 = srcidx[e + 0],  s1 = srcidx[e + 1],  s2 = srcidx[e + 2],  s3 = srcidx[e + 3];
        int s4 = srcidx[e + 4],  s5 = srcidx[e + 5],  s6 = srcidx[e + 6],  s7 = srcidx[e + 7];
        int s8 = srcidx[e + 8],  s9 = srcidx[e + 9],  sa = srcidx[e + 10], sb = srcidx[e + 11];
        int sc = srcidx[e + 12], sd = srcidx[e + 13], se = srcidx[e + 14], sf = srcidx[e + 15];
        float v0 = bf16_to_f32(gl[(size_t)s0 * 64]);
        float v1 = bf16_to_f32(gl[(size_t)s1 * 64]);
        float v2 = bf16_to_f32(gl[(size_t)s2 * 64]);
        float v3 = bf16_to_f32(gl[(size_t)s3 * 64]);
        float v4 = bf16_to_f32(gl[(size_t)s4 * 64]);
        float v5 = bf16_to_f32(gl[(size_t)s5 * 64]);
        float v6 = bf16_to_f32(gl[(size_t)s6 * 64]);
        float v7 = bf16_to_f32(gl[(size_t)s7 * 64]);
        float v8 = bf16_to_f32(gl[(size_t)s8 * 64]);
        float v9 = bf16_to_f32(gl[(size_t)s9 * 64]);
        float va = bf16_to_f32(gl[(size_t)sa * 64]);
        float vb = bf16_to_f32(gl[(size_t)sb * 64]);
        float vc = bf16_to_f32(gl[(size_t)sc * 64]);
        float vd = bf16_to_f32(gl[(size_t)sd * 64]);
        float ve = bf16_to_f32(gl[(size_t)se * 64]);
        float vf = bf16_to_f32(gl[(size_t)sf * 64]);
        float t0 = ((v0 + v1) + (v2 + v3)) + ((v4 + v5) + (v6 + v7));
        float t1 = ((v8 + v9) + (va + vb)) + ((vc + vd) + (ve + vf));
        acc += t0 + t1;
    }
    for (; e + 4 <= end; e += 4) {
        int s0 = srcidx[e + 0], s1 = srcidx[e + 1], s2 = srcidx[e + 2], s3 = srcidx[e + 3];
        float v0 = bf16_to_f32(gl[(size_t)s0 * 64]);
        float v1 = bf16_to_f32(gl[(size_t)s1 * 64]);
        float v2 = bf16_to_f32(gl[(size_t)s2 * 64]);
        float v3 = bf16_to_f32(gl[(size_t)s3 * 64]);
        acc += (v0 + v1) + (v2 + v3);
    }
    for (; e < end; ++e) acc += bf16_to_f32(gl[(size_t)srcidx[e] * 64]);
    float o = fmaf(dinv[node], acc, b[lane]);
    out[(size_t)node * 64 + lane] = relu ? fmaxf(o, 0.f) : o;
}

extern "C" void kernel_launch(void* const* d_in, const int* in_sizes, int n_in,
                              void* d_out, int out_size, void* d_ws, size_t ws_size,
                              hipStream_t stream) {
    const float* x  = (const float*)d_in[0];
    const int*   ei = (const int*)d_in[1];
    const float* W1 = (const float*)d_in[2];
    const float* b1 = (const float*)d_in[3];
    const float* W2 = (const float*)d_in[4];
    const float* b2 = (const float*)d_in[5];
    float* out = (float*)d_out;

    const int n = in_sizes[0] / 64;      // 100000
    const int E = in_sizes[1] / 2;       // 3200000
    const int* src = ei;
    const int* dst = ei + E;
    const int NB = (n + BNODES - 1) >> BSHIFT;         // 391 buckets
    const int chunk = (E + NCH - 1) / NCH;             // 12500 edges/chunk
    const int L = NB * NCH;                            // histogram length

    // workspace carve-up (256B aligned)
    char* ws = (char*)d_ws;
    size_t off = 0;
    auto carve = [&](size_t bytes) { char* p = ws + off; off = (off + bytes + 255) & ~(size_t)255; return p; };
    int*      row_ptr  = (int*)     carve((size_t)(n + 1) * 4);
    int*      partials = (int*)     carve(4096);
    float*    dinv     = (float*)   carve((size_t)n * 4);
    int*      histG    = (int*)     carve((size_t)L * 4);
    int*      histBase = (int*)     carve((size_t)(L + 1) * 4);
    int*      srcidx   = (int*)     carve((size_t)E * 4);
    int*      binned   = (int*)     carve((size_t)E * 4);        // packed src|ldst<<24
    ushort_t* g        = (ushort_t*)carve((size_t)n * 64 * 2);   // bf16 scaled features

    const int nbs_hist = (L + SCAN_CHUNK - 1) / SCAN_CHUNK;      // 98 <= 256

    // ---- CSR build via chunked two-pass radix partition (shared by both layers) ----
    chunk_hist_kernel<<<NCH, HTHREADS, 0, stream>>>(dst, histG, E, NB, chunk);
    block_sum_kernel<<<nbs_hist, 256, 0, stream>>>(histG, partials, L);
    scan_partials_kernel<<<1, 256, 0, stream>>>(partials, nbs_hist, histBase, L);
    scan_write_kernel<<<nbs_hist, 256, 0, stream>>>(histG, partials, histBase, L);
    chunk_scatter_kernel<<<NCH, HTHREADS, 0, stream>>>(src, dst, histBase, binned, E, NB, chunk);
    bucket_finalize_kernel<<<NB, 512, 0, stream>>>(binned, histBase, row_ptr, dinv, srcidx, n);

    const int agg_grid = (n * 64 + 255) / 256;   // one wave per node

    // ---- layer 1: g = bf16((x@W1)*dinv) ; h1 = relu(dinv*(agg(g)+g)+b1) -> d_out (f32) ----
    transform_kernel<<<2048, 256, 0, stream>>>(x, W1, dinv, g, n);
    aggregate_kernel<<<agg_grid, 256, 0, stream>>>(g, row_ptr, srcidx, dinv, b1, out, n, 1);

    // ---- layer 2: g = bf16((h1@W2)*dinv) ; out = dinv*(agg(g)+g)+b2 ----
    transform_kernel<<<2048, 256, 0, stream>>>(out, W2, dinv, g, n);
    aggregate_kernel<<<agg_grid, 256, 0, stream>>>(g, row_ptr, srcidx, dinv, b2, out, n, 0);
}